// Round 14
// baseline (161.606 us; speedup 1.0000x reference)
//
#include <hip/hip_runtime.h>
#include <hip/hip_bf16.h>

// ---------------------------------------------------------------------------
// Actor forward pass, fp32 (7 launches). R8 base with K1 split:
//   K0:  tiled transposes w1->w1t, w2->w2t
//   Kp:  maxpool, PURE LINEAR x read (92KB slab/block) -> xp [4][2][6][60][60][48]
//   K1:  conv1+BN+ReLU, stages pooled patch from L3-resident xp
//   K2:  conv2+BN+ReLU
//   K3:  conv4 split-K (kc=10, nontemporal w4)
//   K4:  feat+BN+ReLU+concat + lin1 268->512+BN+ReLU
//   K5:  lin2 512->6 + tanh
// ---------------------------------------------------------------------------

typedef float f32x4_t __attribute__((ext_vector_type(4)));

__device__ __forceinline__ float wave_reduce(float v) {
#pragma unroll
    for (int off = 32; off > 0; off >>= 1) v += __shfl_down(v, off);
    return v;
}

// K0: tiled transposes, both read and write coalesced.
__global__ __launch_bounds__(256) void k_prep(
    const float* __restrict__ w1, const float* __restrict__ w2,
    float* __restrict__ w1t, float* __restrict__ w2t) {
    int tid = threadIdx.x;
    if (blockIdx.x < 64) {
        __shared__ float tile[32][65];
        int oc = blockIdx.x >> 4;
        int tc = blockIdx.x & 15;
        int o0 = oc * 32, t0 = tc * 64;
        int ol = tid >> 6, tl = tid & 63;
#pragma unroll
        for (int p = 0; p < 8; ++p) {
            int o = ol + p * 4;
            tile[o][tl] = w2[(size_t)(o0 + o) * 1024 + t0 + tl];
        }
        __syncthreads();
        int ow = tid & 31, tw = tid >> 5;
#pragma unroll
        for (int p = 0; p < 8; ++p) {
            int t = tw + p * 8;
            w2t[(size_t)(t0 + t) * 128 + o0 + ow] = tile[ow][t];
        }
        return;
    }
    for (int i = (blockIdx.x - 64) * 256 + tid; i < 64 * 162; i += 16 * 256) {
        int t = i >> 6, o = i & 63;
        w1t[i] = w1[o * 162 + t];
    }
}

// Kp: linear-slab maxpool. grid: 4*2*6*60 = 2880 blocks of 256.
// Block reads one 92160B contiguous slab (2 x-rows), writes 11520B contiguous.
__global__ __launch_bounds__(256) void k_pool(
    const float* __restrict__ x, float* __restrict__ xp) {
    int b = blockIdx.x;
    int xq = b % 60; int r = b / 60;
    int tr = r % 6;  r /= 6;
    int c  = r % 2;  int n = r / 2;
    int tid = threadIdx.x;

    __shared__ float zbuf[11520];  // [xi2][yr120][zh48] = 45 KB

    const float4* slab = (const float4*)(x + ((((size_t)n * 2 + c) * 6 + tr) * 120 + 2 * xq) * 11520);
    // pass A: fully linear read of 5760 float4, z-pair max
    for (int f = tid; f < 5760; f += 256) {
        float4 v = slab[f];  // consecutive lanes -> consecutive 16B: pure stream
        int xi = f / 2880, rem = f - xi * 2880;   // rem = yr*24 + q
        *(float2*)&zbuf[xi * 5760 + rem * 2] = make_float2(fmaxf(v.x, v.y), fmaxf(v.z, v.w));
    }
    __syncthreads();
    // pass B: x-pair & y-pair max, contiguous write
    float* outb = xp + (size_t)b * 2880;  // [((n,c,tr)*60+xq)][yp60][zp48]
    for (int o = tid; o < 2880; o += 256) {
        int yp = o / 48, zp = o - yp * 48;
        const float* z0 = &zbuf[2 * yp * 48 + zp];
        float m = fmaxf(fmaxf(z0[0], z0[48]), fmaxf(z0[5760], z0[5760 + 48]));
        outb[o] = m;
    }
}

// K1: conv1 + BN + ReLU. grid: 3200 blocks of 256. Stages from L3-resident xp.
__global__ __launch_bounds__(256) void k_conv1(
    const float* __restrict__ xp, const float* __restrict__ w1t,
    const float* __restrict__ b1, const float* __restrict__ g1,
    const float* __restrict__ be1, const float* __restrict__ m1,
    const float* __restrict__ v1, float* __restrict__ y1) {
    int bid = blockIdx.x;
    int yo = bid % 20; bid /= 20;
    int xo = bid % 20; bid /= 20;
    int t  = bid % 2;  bid /= 2;
    int n  = bid;
    int tid = threadIdx.x;

    __shared__ float pooled[2592];  // [row54][kz3][zo16]

    // stage 648 float4 = 18 segments (c,tp,px) x 144 floats (py3 x zq48)
    for (int task = tid; task < 648; task += 256) {
        int seg = task / 36, rem = task - seg * 36;
        int c = seg / 9, tp = (seg % 9) / 3, px = seg % 3;
        const float* src = xp + ((((size_t)n * 2 + c) * 6 + 3 * t + tp) * 60 + 3 * xo + px) * 2880
                              + (size_t)(3 * yo) * 48 + rem * 4;
        float4 v = *(const float4*)src;
        int zz = rem * 4;
        int py = zz / 48, zq = zz - py * 48;
        int row = ((c * 3 + tp) * 3 + px) * 3 + py;
        float vs[4] = {v.x, v.y, v.z, v.w};
#pragma unroll
        for (int j = 0; j < 4; ++j) {
            int z = zq + j;
            pooled[row * 48 + (z % 3) * 16 + z / 3] = vs[j];
        }
    }
    __syncthreads();

    // compute phase (identical to R8)
    int o  = tid & 63;
    int zg = tid >> 6;
    float acc[4] = {0.f, 0.f, 0.f, 0.f};
    for (int row = 0; row < 54; ++row) {
        const float* pr = &pooled[row * 48 + zg * 4];
#pragma unroll
        for (int kz = 0; kz < 3; ++kz) {
            float w = w1t[(row * 3 + kz) * 64 + o];
            float4 pv = *(const float4*)(pr + kz * 16);
            acc[0] = fmaf(w, pv.x, acc[0]);
            acc[1] = fmaf(w, pv.y, acc[1]);
            acc[2] = fmaf(w, pv.z, acc[2]);
            acc[3] = fmaf(w, pv.w, acc[3]);
        }
    }
    float s  = g1[o] * rsqrtf(v1[o] + 1e-5f);
    float sh = be1[o] + (b1[o] - m1[o]) * s;
    size_t obase = ((((size_t)n * 64 + o) * 2 + t) * 20 + xo) * 320 + (size_t)yo * 16 + zg * 4;
    float4 outv;
    outv.x = fmaxf(acc[0] * s + sh, 0.f);
    outv.y = fmaxf(acc[1] * s + sh, 0.f);
    outv.z = fmaxf(acc[2] * s + sh, 0.f);
    outv.w = fmaxf(acc[3] * s + sh, 0.f);
    *(float4*)&y1[obase] = outv;
}

// K2: conv2 + BN + ReLU. grid: 400 blocks of 512
__global__ __launch_bounds__(512) void k_conv2(
    const float* __restrict__ y1, const float* __restrict__ w2t,
    const float* __restrict__ b2, const float* __restrict__ g2,
    const float* __restrict__ be2, const float* __restrict__ m2,
    const float* __restrict__ v2, float* __restrict__ y2) {
    int bid = blockIdx.x;
    int yo = bid % 10; bid /= 10;
    int xo = bid % 10; bid /= 10;
    int n  = bid;

    __shared__ float in2t[8192];
    __shared__ float red[8192];
    int tid = threadIdx.x;
#pragma unroll
    for (int it = 0; it < 4; ++it) {
        int task = tid + it * 512;
        int a = task & 3; int row = task >> 2;
        int ky = row & 1, kx = (row >> 1) & 1, kt = (row >> 2) & 1, c = row >> 3;
        const float* src = y1 + ((((size_t)n * 64 + c) * 2 + kt) * 20 + 2 * xo + kx) * 320
                              + (size_t)(2 * yo + ky) * 16 + 4 * a;
        float4 v = *(const float4*)src;
        *(float2*)&in2t[row * 8 + 2 * a]        = make_float2(v.x, v.z);
        *(float2*)&in2t[4096 + row * 8 + 2 * a] = make_float2(v.y, v.w);
    }
    __syncthreads();

    int o2 = tid & 63;
    int ks = tid >> 6;
    float acc[2][8];
#pragma unroll
    for (int a = 0; a < 2; ++a)
#pragma unroll
        for (int b = 0; b < 8; ++b) acc[a][b] = 0.f;

    for (int rr = 0; rr < 64; ++rr) {
        int row = ks * 64 + rr;
#pragma unroll
        for (int kz = 0; kz < 2; ++kz) {
            float2 w = *(const float2*)&w2t[(row * 2 + kz) * 128 + 2 * o2];
            float4 p0 = *(const float4*)&in2t[kz * 4096 + row * 8];
            float4 p1 = *(const float4*)&in2t[kz * 4096 + row * 8 + 4];
            acc[0][0] = fmaf(w.x, p0.x, acc[0][0]);
            acc[0][1] = fmaf(w.x, p0.y, acc[0][1]);
            acc[0][2] = fmaf(w.x, p0.z, acc[0][2]);
            acc[0][3] = fmaf(w.x, p0.w, acc[0][3]);
            acc[0][4] = fmaf(w.x, p1.x, acc[0][4]);
            acc[0][5] = fmaf(w.x, p1.y, acc[0][5]);
            acc[0][6] = fmaf(w.x, p1.z, acc[0][6]);
            acc[0][7] = fmaf(w.x, p1.w, acc[0][7]);
            acc[1][0] = fmaf(w.y, p0.x, acc[1][0]);
            acc[1][1] = fmaf(w.y, p0.y, acc[1][1]);
            acc[1][2] = fmaf(w.y, p0.z, acc[1][2]);
            acc[1][3] = fmaf(w.y, p0.w, acc[1][3]);
            acc[1][4] = fmaf(w.y, p1.x, acc[1][4]);
            acc[1][5] = fmaf(w.y, p1.y, acc[1][5]);
            acc[1][6] = fmaf(w.y, p1.z, acc[1][6]);
            acc[1][7] = fmaf(w.y, p1.w, acc[1][7]);
        }
    }
#pragma unroll
    for (int a = 0; a < 2; ++a)
#pragma unroll
        for (int b = 0; b < 8; ++b) red[ks * 1024 + o2 * 16 + a * 8 + b] = acc[a][b];
    __syncthreads();

#pragma unroll
    for (int e = tid; e < 1024; e += 512) {
        float v = 0.f;
#pragma unroll
        for (int k = 0; k < 8; ++k) v += red[k * 1024 + e];
        int o2e = e >> 4, i = e & 15;
        int o = o2e * 2 + (i >> 3), zo = i & 7;
        float s  = g2[o] * rsqrtf(v2[o] + 1e-5f);
        float sh = be2[o] + (b2[o] - m2[o]) * s;
        y2[(((size_t)n * 128 + o) * 10 + xo) * 80 + (size_t)yo * 8 + zo] = fmaxf(v * s + sh, 0.f);
    }
}

// K3: conv4 split-K partials. grid: 640 blocks of 256
__global__ __launch_bounds__(256) void k_conv4(
    const float* __restrict__ y2, const float* __restrict__ w4,
    float* __restrict__ part) {
    int oc = blockIdx.x & 63;
    int kc = blockIdx.x >> 6;
    int tid = threadIdx.x;
    const float4* y2v = (const float4*)y2;
    const f32x4_t* w4v = (const f32x4_t*)w4;
    float acc[4][4];
#pragma unroll
    for (int a = 0; a < 4; ++a)
#pragma unroll
        for (int b = 0; b < 4; ++b) acc[a][b] = 0.f;

    int base = kc * 2560;
#pragma unroll 2
    for (int i = 0; i < 10; ++i) {
        int f4 = base + i * 256 + tid;
        float4 a0 = y2v[f4];
        float4 a1 = y2v[25600 + f4];
        float4 a2 = y2v[51200 + f4];
        float4 a3 = y2v[76800 + f4];
#pragma unroll
        for (int oo = 0; oo < 4; ++oo) {
            f32x4_t w = __builtin_nontemporal_load(&w4v[(size_t)(oc * 4 + oo) * 25600 + f4]);
            acc[oo][0] = fmaf(w.x, a0.x, fmaf(w.y, a0.y, fmaf(w.z, a0.z, fmaf(w.w, a0.w, acc[oo][0]))));
            acc[oo][1] = fmaf(w.x, a1.x, fmaf(w.y, a1.y, fmaf(w.z, a1.z, fmaf(w.w, a1.w, acc[oo][1]))));
            acc[oo][2] = fmaf(w.x, a2.x, fmaf(w.y, a2.y, fmaf(w.z, a2.z, fmaf(w.w, a2.w, acc[oo][2]))));
            acc[oo][3] = fmaf(w.x, a3.x, fmaf(w.y, a3.y, fmaf(w.z, a3.z, fmaf(w.w, a3.w, acc[oo][3]))));
        }
    }
    __shared__ float red[4][16];
    int wave = tid >> 6, lane = tid & 63;
#pragma unroll
    for (int oo = 0; oo < 4; ++oo)
#pragma unroll
        for (int nn = 0; nn < 4; ++nn) {
            float v = wave_reduce(acc[oo][nn]);
            if (lane == 0) red[wave][oo * 4 + nn] = v;
        }
    __syncthreads();
    if (tid < 16) {
        float sum = red[0][tid] + red[1][tid] + red[2][tid] + red[3][tid];
        part[(size_t)blockIdx.x * 16 + tid] = sum;
    }
}

// K4: feat reduce + BN + ReLU + concat + linear 268->512 + BN + ReLU.
__global__ __launch_bounds__(256) void k_lin1(
    const float* __restrict__ part, const float* __restrict__ b4,
    const float* __restrict__ gn, const float* __restrict__ ben,
    const float* __restrict__ mn, const float* __restrict__ vn,
    const float* __restrict__ jp, const float* __restrict__ jg,
    const float* __restrict__ wl, const float* __restrict__ bl,
    const float* __restrict__ gl, const float* __restrict__ bel,
    const float* __restrict__ ml, const float* __restrict__ vl,
    float* __restrict__ h2) {
    __shared__ float feat[4 * 268];
    int tid = threadIdx.x;
    {
        int o = tid;
        int oc = o >> 2, oo = o & 3;
        float s  = gn[o] * rsqrtf(vn[o] + 1e-5f);
        float sh = ben[o] + (b4[o] - mn[o]) * s;
#pragma unroll
        for (int nn = 0; nn < 4; ++nn) {
            float acc = 0.f;
#pragma unroll
            for (int kc = 0; kc < 10; ++kc) acc += part[(kc * 64 + oc) * 16 + oo * 4 + nn];
            feat[nn * 268 + 12 + o] = fmaxf(acc * s + sh, 0.f);
        }
        if (o < 24) {
            int nn = o / 6, j = o % 6;
            feat[nn * 268 + j] = jp[o];
            feat[nn * 268 + 6 + j] = jg[o];
        }
    }
    __syncthreads();

    int wave = tid >> 6, lane = tid & 63;
    int j = blockIdx.x * 4 + wave;
    const float* wr = wl + (size_t)j * 268;
    float acc[4] = {0.f, 0.f, 0.f, 0.f};
    for (int k = lane; k < 268; k += 64) {
        float w = wr[k];
#pragma unroll
        for (int nn = 0; nn < 4; ++nn) acc[nn] = fmaf(w, feat[nn * 268 + k], acc[nn]);
    }
#pragma unroll
    for (int nn = 0; nn < 4; ++nn) acc[nn] = wave_reduce(acc[nn]);
    if (lane == 0) {
        float s  = gl[j] * rsqrtf(vl[j] + 1e-5f);
        float sh = bel[j] + (bl[j] - ml[j]) * s;
#pragma unroll
        for (int nn = 0; nn < 4; ++nn) h2[nn * 512 + j] = fmaxf(acc[nn] * s + sh, 0.f);
    }
}

// K5: linear 512->6 + tanh. 1 block of 256
__global__ void k_lin2(const float* __restrict__ h2, const float* __restrict__ wo,
                       const float* __restrict__ bo, float* __restrict__ out) {
    int wave = threadIdx.x >> 6, lane = threadIdx.x & 63;
    int n = wave;
    float hv[8];
#pragma unroll
    for (int i = 0; i < 8; ++i) hv[i] = h2[n * 512 + i * 64 + lane];
    for (int o = 0; o < 6; ++o) {
        float acc = 0.f;
#pragma unroll
        for (int i = 0; i < 8; ++i) acc = fmaf(hv[i], wo[o * 512 + i * 64 + lane], acc);
        acc = wave_reduce(acc);
        if (lane == 0) out[n * 6 + o] = tanhf(acc + bo[o]);
    }
}

extern "C" void kernel_launch(void* const* d_in, const int* in_sizes, int n_in,
                              void* d_out, int out_size, void* d_ws, size_t ws_size,
                              hipStream_t stream) {
    const float* x   = (const float*)d_in[0];
    const float* jp  = (const float*)d_in[1];
    const float* jg  = (const float*)d_in[2];
    const float* w1  = (const float*)d_in[3];
    const float* b1  = (const float*)d_in[4];
    const float* g1  = (const float*)d_in[5];
    const float* be1 = (const float*)d_in[6];
    const float* m1  = (const float*)d_in[7];
    const float* v1  = (const float*)d_in[8];
    const float* w2  = (const float*)d_in[9];
    const float* b2  = (const float*)d_in[10];
    const float* g2  = (const float*)d_in[11];
    const float* be2 = (const float*)d_in[12];
    const float* m2  = (const float*)d_in[13];
    const float* v2  = (const float*)d_in[14];
    const float* w4  = (const float*)d_in[15];
    const float* b4  = (const float*)d_in[16];
    const float* gn  = (const float*)d_in[17];
    const float* ben = (const float*)d_in[18];
    const float* mn  = (const float*)d_in[19];
    const float* vn  = (const float*)d_in[20];
    const float* wl  = (const float*)d_in[21];
    const float* bl  = (const float*)d_in[22];
    const float* gl  = (const float*)d_in[23];
    const float* bel = (const float*)d_in[24];
    const float* ml  = (const float*)d_in[25];
    const float* vl  = (const float*)d_in[26];
    const float* wo  = (const float*)d_in[27];
    const float* bo  = (const float*)d_in[28];
    float* out = (float*)d_out;

    float* ws   = (float*)d_ws;
    float* w1t  = ws;                 // 10368
    float* w2t  = ws + 10368;         // 131072
    float* y1   = ws + 141440;        // 3276800
    float* y2   = ws + 3418240;       // 409600
    float* part = ws + 3827840;       // 10240 (640*16)
    float* h2   = ws + 3838080;       // 2048
    float* xp   = ws + 3840128;       // 8294400 (33 MB)

    k_prep<<<80, 256, 0, stream>>>(w1, w2, w1t, w2t);
    k_pool<<<2880, 256, 0, stream>>>(x, xp);
    k_conv1<<<3200, 256, 0, stream>>>(xp, w1t, b1, g1, be1, m1, v1, y1);
    k_conv2<<<400, 512, 0, stream>>>(y1, w2t, b2, g2, be2, m2, v2, y2);
    k_conv4<<<640, 256, 0, stream>>>(y2, w4, part);
    k_lin1<<<128, 256, 0, stream>>>(part, b4, gn, ben, mn, vn, jp, jg,
                                    wl, bl, gl, bel, ml, vl, h2);
    k_lin2<<<1, 256, 0, stream>>>(h2, wo, bo, out);
}

// Round 15
// 122.145 us; speedup vs baseline: 1.3231x; 1.3231x over previous
//
#include <hip/hip_runtime.h>
#include <hip/hip_bf16.h>

// ---------------------------------------------------------------------------
// Actor forward pass, fp32, fused pipeline (6 launches) — proven optimum (R8):
//   K0: transpose w1 -> w1t [162][64], w2 -> w2t [1024][128] (LDS-tiled)
//   K1: maxpool(1,2,2,2) + conv1(2->64,k3,s3) + BN + ReLU     -> y1
//   K2: conv2(64->128,k2,s2) + BN + ReLU                      -> y2
//   K3: conv4(128->256) split-K partial sums (kc=10, nt w4)   -> part [640][16]
//   K4: feat reduce+BN+ReLU+concat -> lin1 268->512+BN+ReLU   -> h2
//   K5: lin2 512->6 + tanh                                    -> out
// ---------------------------------------------------------------------------

typedef float f32x4_t __attribute__((ext_vector_type(4)));

__device__ __forceinline__ float wave_reduce(float v) {
#pragma unroll
    for (int off = 32; off > 0; off >>= 1) v += __shfl_down(v, off);
    return v;
}

// K0: tiled transposes, both read and write coalesced.
__global__ __launch_bounds__(256) void k_prep(
    const float* __restrict__ w1, const float* __restrict__ w2,
    float* __restrict__ w1t, float* __restrict__ w2t) {
    int tid = threadIdx.x;
    if (blockIdx.x < 64) {
        __shared__ float tile[32][65];
        int oc = blockIdx.x >> 4;
        int tc = blockIdx.x & 15;
        int o0 = oc * 32, t0 = tc * 64;
        int ol = tid >> 6, tl = tid & 63;
#pragma unroll
        for (int p = 0; p < 8; ++p) {
            int o = ol + p * 4;
            tile[o][tl] = w2[(size_t)(o0 + o) * 1024 + t0 + tl];
        }
        __syncthreads();
        int ow = tid & 31, tw = tid >> 5;
#pragma unroll
        for (int p = 0; p < 8; ++p) {
            int t = tw + p * 8;
            w2t[(size_t)(t0 + t) * 128 + o0 + ow] = tile[ow][t];
        }
        return;
    }
    for (int i = (blockIdx.x - 64) * 256 + tid; i < 64 * 162; i += 16 * 256) {
        int t = i >> 6, o = i & 63;
        w1t[i] = w1[o * 162 + t];
    }
}

// K1: fused maxpool + conv1 + BN + ReLU. grid: 3200 blocks of 256
__global__ __launch_bounds__(256) void k_conv1(
    const float* __restrict__ x, const float* __restrict__ w1t,
    const float* __restrict__ b1, const float* __restrict__ g1,
    const float* __restrict__ be1, const float* __restrict__ m1,
    const float* __restrict__ v1, float* __restrict__ y1) {
    int bid = blockIdx.x;
    int yo = bid % 20; bid /= 20;
    int xo = bid % 20; bid /= 20;
    int t  = bid % 2;  bid /= 2;
    int n  = bid;

    __shared__ float pooled[2592];
    int tid = threadIdx.x;

    for (int task = tid; task < 1296; task += 256) {
        int q = task % 24; int r = task / 24;
        int py = r % 3; r /= 3;
        int px = r % 3; r /= 3;
        int tp = r % 3; int c = r / 3;
        const float* base = x + ((((size_t)n * 2 + c) * 6 + 3 * t + tp) * 120 + 6 * xo + 2 * px) * 11520
                              + (size_t)(6 * yo + 2 * py) * 96 + 4 * q;
        float4 v00 = *(const float4*)(base);
        float4 v01 = *(const float4*)(base + 96);
        float4 v10 = *(const float4*)(base + 11520);
        float4 v11 = *(const float4*)(base + 11520 + 96);
        float p0 = fmaxf(fmaxf(fmaxf(v00.x, v00.y), fmaxf(v01.x, v01.y)),
                         fmaxf(fmaxf(v10.x, v10.y), fmaxf(v11.x, v11.y)));
        float p1 = fmaxf(fmaxf(fmaxf(v00.z, v00.w), fmaxf(v01.z, v01.w)),
                         fmaxf(fmaxf(v10.z, v10.w), fmaxf(v11.z, v11.w)));
        int row = ((c * 3 + tp) * 3 + px) * 3 + py;
        int z0 = 2 * q, z1 = 2 * q + 1;
        pooled[row * 48 + (z0 % 3) * 16 + z0 / 3] = p0;
        pooled[row * 48 + (z1 % 3) * 16 + z1 / 3] = p1;
    }
    __syncthreads();

    int o  = tid & 63;
    int zg = tid >> 6;
    float acc[4] = {0.f, 0.f, 0.f, 0.f};
    for (int row = 0; row < 54; ++row) {
        const float* pr = &pooled[row * 48 + zg * 4];
#pragma unroll
        for (int kz = 0; kz < 3; ++kz) {
            float w = w1t[(row * 3 + kz) * 64 + o];
            float4 pv = *(const float4*)(pr + kz * 16);
            acc[0] = fmaf(w, pv.x, acc[0]);
            acc[1] = fmaf(w, pv.y, acc[1]);
            acc[2] = fmaf(w, pv.z, acc[2]);
            acc[3] = fmaf(w, pv.w, acc[3]);
        }
    }
    float s  = g1[o] * rsqrtf(v1[o] + 1e-5f);
    float sh = be1[o] + (b1[o] - m1[o]) * s;
    size_t obase = ((((size_t)n * 64 + o) * 2 + t) * 20 + xo) * 320 + (size_t)yo * 16 + zg * 4;
    float4 outv;
    outv.x = fmaxf(acc[0] * s + sh, 0.f);
    outv.y = fmaxf(acc[1] * s + sh, 0.f);
    outv.z = fmaxf(acc[2] * s + sh, 0.f);
    outv.w = fmaxf(acc[3] * s + sh, 0.f);
    *(float4*)&y1[obase] = outv;
}

// K2: conv2 + BN + ReLU. grid: 400 blocks of 512
__global__ __launch_bounds__(512) void k_conv2(
    const float* __restrict__ y1, const float* __restrict__ w2t,
    const float* __restrict__ b2, const float* __restrict__ g2,
    const float* __restrict__ be2, const float* __restrict__ m2,
    const float* __restrict__ v2, float* __restrict__ y2) {
    int bid = blockIdx.x;
    int yo = bid % 10; bid /= 10;
    int xo = bid % 10; bid /= 10;
    int n  = bid;

    __shared__ float in2t[8192];
    __shared__ float red[8192];
    int tid = threadIdx.x;
#pragma unroll
    for (int it = 0; it < 4; ++it) {
        int task = tid + it * 512;
        int a = task & 3; int row = task >> 2;
        int ky = row & 1, kx = (row >> 1) & 1, kt = (row >> 2) & 1, c = row >> 3;
        const float* src = y1 + ((((size_t)n * 64 + c) * 2 + kt) * 20 + 2 * xo + kx) * 320
                              + (size_t)(2 * yo + ky) * 16 + 4 * a;
        float4 v = *(const float4*)src;
        *(float2*)&in2t[row * 8 + 2 * a]        = make_float2(v.x, v.z);
        *(float2*)&in2t[4096 + row * 8 + 2 * a] = make_float2(v.y, v.w);
    }
    __syncthreads();

    int o2 = tid & 63;
    int ks = tid >> 6;
    float acc[2][8];
#pragma unroll
    for (int a = 0; a < 2; ++a)
#pragma unroll
        for (int b = 0; b < 8; ++b) acc[a][b] = 0.f;

    for (int rr = 0; rr < 64; ++rr) {
        int row = ks * 64 + rr;
#pragma unroll
        for (int kz = 0; kz < 2; ++kz) {
            float2 w = *(const float2*)&w2t[(row * 2 + kz) * 128 + 2 * o2];
            float4 p0 = *(const float4*)&in2t[kz * 4096 + row * 8];
            float4 p1 = *(const float4*)&in2t[kz * 4096 + row * 8 + 4];
            acc[0][0] = fmaf(w.x, p0.x, acc[0][0]);
            acc[0][1] = fmaf(w.x, p0.y, acc[0][1]);
            acc[0][2] = fmaf(w.x, p0.z, acc[0][2]);
            acc[0][3] = fmaf(w.x, p0.w, acc[0][3]);
            acc[0][4] = fmaf(w.x, p1.x, acc[0][4]);
            acc[0][5] = fmaf(w.x, p1.y, acc[0][5]);
            acc[0][6] = fmaf(w.x, p1.z, acc[0][6]);
            acc[0][7] = fmaf(w.x, p1.w, acc[0][7]);
            acc[1][0] = fmaf(w.y, p0.x, acc[1][0]);
            acc[1][1] = fmaf(w.y, p0.y, acc[1][1]);
            acc[1][2] = fmaf(w.y, p0.z, acc[1][2]);
            acc[1][3] = fmaf(w.y, p0.w, acc[1][3]);
            acc[1][4] = fmaf(w.y, p1.x, acc[1][4]);
            acc[1][5] = fmaf(w.y, p1.y, acc[1][5]);
            acc[1][6] = fmaf(w.y, p1.z, acc[1][6]);
            acc[1][7] = fmaf(w.y, p1.w, acc[1][7]);
        }
    }
#pragma unroll
    for (int a = 0; a < 2; ++a)
#pragma unroll
        for (int b = 0; b < 8; ++b) red[ks * 1024 + o2 * 16 + a * 8 + b] = acc[a][b];
    __syncthreads();

#pragma unroll
    for (int e = tid; e < 1024; e += 512) {
        float v = 0.f;
#pragma unroll
        for (int k = 0; k < 8; ++k) v += red[k * 1024 + e];
        int o2e = e >> 4, i = e & 15;
        int o = o2e * 2 + (i >> 3), zo = i & 7;
        float s  = g2[o] * rsqrtf(v2[o] + 1e-5f);
        float sh = be2[o] + (b2[o] - m2[o]) * s;
        y2[(((size_t)n * 128 + o) * 10 + xo) * 80 + (size_t)yo * 8 + zo] = fmaxf(v * s + sh, 0.f);
    }
}

// K3: conv4 split-K partials. grid: 640 blocks of 256
__global__ __launch_bounds__(256) void k_conv4(
    const float* __restrict__ y2, const float* __restrict__ w4,
    float* __restrict__ part) {
    int oc = blockIdx.x & 63;
    int kc = blockIdx.x >> 6;
    int tid = threadIdx.x;
    const float4* y2v = (const float4*)y2;
    const f32x4_t* w4v = (const f32x4_t*)w4;
    float acc[4][4];
#pragma unroll
    for (int a = 0; a < 4; ++a)
#pragma unroll
        for (int b = 0; b < 4; ++b) acc[a][b] = 0.f;

    int base = kc * 2560;
#pragma unroll 2
    for (int i = 0; i < 10; ++i) {
        int f4 = base + i * 256 + tid;
        float4 a0 = y2v[f4];
        float4 a1 = y2v[25600 + f4];
        float4 a2 = y2v[51200 + f4];
        float4 a3 = y2v[76800 + f4];
#pragma unroll
        for (int oo = 0; oo < 4; ++oo) {
            f32x4_t w = __builtin_nontemporal_load(&w4v[(size_t)(oc * 4 + oo) * 25600 + f4]);
            acc[oo][0] = fmaf(w.x, a0.x, fmaf(w.y, a0.y, fmaf(w.z, a0.z, fmaf(w.w, a0.w, acc[oo][0]))));
            acc[oo][1] = fmaf(w.x, a1.x, fmaf(w.y, a1.y, fmaf(w.z, a1.z, fmaf(w.w, a1.w, acc[oo][1]))));
            acc[oo][2] = fmaf(w.x, a2.x, fmaf(w.y, a2.y, fmaf(w.z, a2.z, fmaf(w.w, a2.w, acc[oo][2]))));
            acc[oo][3] = fmaf(w.x, a3.x, fmaf(w.y, a3.y, fmaf(w.z, a3.z, fmaf(w.w, a3.w, acc[oo][3]))));
        }
    }
    __shared__ float red[4][16];
    int wave = tid >> 6, lane = tid & 63;
#pragma unroll
    for (int oo = 0; oo < 4; ++oo)
#pragma unroll
        for (int nn = 0; nn < 4; ++nn) {
            float v = wave_reduce(acc[oo][nn]);
            if (lane == 0) red[wave][oo * 4 + nn] = v;
        }
    __syncthreads();
    if (tid < 16) {
        float sum = red[0][tid] + red[1][tid] + red[2][tid] + red[3][tid];
        part[(size_t)blockIdx.x * 16 + tid] = sum;
    }
}

// K4: feat reduce + BN + ReLU + concat + linear 268->512 + BN + ReLU.
__global__ __launch_bounds__(256) void k_lin1(
    const float* __restrict__ part, const float* __restrict__ b4,
    const float* __restrict__ gn, const float* __restrict__ ben,
    const float* __restrict__ mn, const float* __restrict__ vn,
    const float* __restrict__ jp, const float* __restrict__ jg,
    const float* __restrict__ wl, const float* __restrict__ bl,
    const float* __restrict__ gl, const float* __restrict__ bel,
    const float* __restrict__ ml, const float* __restrict__ vl,
    float* __restrict__ h2) {
    __shared__ float feat[4 * 268];
    int tid = threadIdx.x;
    {
        int o = tid;
        int oc = o >> 2, oo = o & 3;
        float s  = gn[o] * rsqrtf(vn[o] + 1e-5f);
        float sh = ben[o] + (b4[o] - mn[o]) * s;
#pragma unroll
        for (int nn = 0; nn < 4; ++nn) {
            float acc = 0.f;
#pragma unroll
            for (int kc = 0; kc < 10; ++kc) acc += part[(kc * 64 + oc) * 16 + oo * 4 + nn];
            feat[nn * 268 + 12 + o] = fmaxf(acc * s + sh, 0.f);
        }
        if (o < 24) {
            int nn = o / 6, j = o % 6;
            feat[nn * 268 + j] = jp[o];
            feat[nn * 268 + 6 + j] = jg[o];
        }
    }
    __syncthreads();

    int wave = tid >> 6, lane = tid & 63;
    int j = blockIdx.x * 4 + wave;
    const float* wr = wl + (size_t)j * 268;
    float acc[4] = {0.f, 0.f, 0.f, 0.f};
    for (int k = lane; k < 268; k += 64) {
        float w = wr[k];
#pragma unroll
        for (int nn = 0; nn < 4; ++nn) acc[nn] = fmaf(w, feat[nn * 268 + k], acc[nn]);
    }
#pragma unroll
    for (int nn = 0; nn < 4; ++nn) acc[nn] = wave_reduce(acc[nn]);
    if (lane == 0) {
        float s  = gl[j] * rsqrtf(vl[j] + 1e-5f);
        float sh = bel[j] + (bl[j] - ml[j]) * s;
#pragma unroll
        for (int nn = 0; nn < 4; ++nn) h2[nn * 512 + j] = fmaxf(acc[nn] * s + sh, 0.f);
    }
}

// K5: linear 512->6 + tanh. 1 block of 256
__global__ void k_lin2(const float* __restrict__ h2, const float* __restrict__ wo,
                       const float* __restrict__ bo, float* __restrict__ out) {
    int wave = threadIdx.x >> 6, lane = threadIdx.x & 63;
    int n = wave;
    float hv[8];
#pragma unroll
    for (int i = 0; i < 8; ++i) hv[i] = h2[n * 512 + i * 64 + lane];
    for (int o = 0; o < 6; ++o) {
        float acc = 0.f;
#pragma unroll
        for (int i = 0; i < 8; ++i) acc = fmaf(hv[i], wo[o * 512 + i * 64 + lane], acc);
        acc = wave_reduce(acc);
        if (lane == 0) out[n * 6 + o] = tanhf(acc + bo[o]);
    }
}

extern "C" void kernel_launch(void* const* d_in, const int* in_sizes, int n_in,
                              void* d_out, int out_size, void* d_ws, size_t ws_size,
                              hipStream_t stream) {
    const float* x   = (const float*)d_in[0];
    const float* jp  = (const float*)d_in[1];
    const float* jg  = (const float*)d_in[2];
    const float* w1  = (const float*)d_in[3];
    const float* b1  = (const float*)d_in[4];
    const float* g1  = (const float*)d_in[5];
    const float* be1 = (const float*)d_in[6];
    const float* m1  = (const float*)d_in[7];
    const float* v1  = (const float*)d_in[8];
    const float* w2  = (const float*)d_in[9];
    const float* b2  = (const float*)d_in[10];
    const float* g2  = (const float*)d_in[11];
    const float* be2 = (const float*)d_in[12];
    const float* m2  = (const float*)d_in[13];
    const float* v2  = (const float*)d_in[14];
    const float* w4  = (const float*)d_in[15];
    const float* b4  = (const float*)d_in[16];
    const float* gn  = (const float*)d_in[17];
    const float* ben = (const float*)d_in[18];
    const float* mn  = (const float*)d_in[19];
    const float* vn  = (const float*)d_in[20];
    const float* wl  = (const float*)d_in[21];
    const float* bl  = (const float*)d_in[22];
    const float* gl  = (const float*)d_in[23];
    const float* bel = (const float*)d_in[24];
    const float* ml  = (const float*)d_in[25];
    const float* vl  = (const float*)d_in[26];
    const float* wo  = (const float*)d_in[27];
    const float* bo  = (const float*)d_in[28];
    float* out = (float*)d_out;

    float* ws   = (float*)d_ws;
    float* w1t  = ws;                 // 10368
    float* w2t  = ws + 10368;         // 131072
    float* y1   = ws + 141440;        // 3276800
    float* y2   = ws + 3418240;       // 409600
    float* part = ws + 3827840;       // 10240 (640*16)
    float* h2   = ws + 3838080;       // 2048

    k_prep<<<80, 256, 0, stream>>>(w1, w2, w1t, w2t);
    k_conv1<<<3200, 256, 0, stream>>>(x, w1t, b1, g1, be1, m1, v1, y1);
    k_conv2<<<400, 512, 0, stream>>>(y1, w2t, b2, g2, be2, m2, v2, y2);
    k_conv4<<<640, 256, 0, stream>>>(y2, w4, part);
    k_lin1<<<128, 256, 0, stream>>>(part, b4, gn, ben, mn, vn, jp, jg,
                                    wl, bl, gl, bel, ml, vl, h2);
    k_lin2<<<1, 256, 0, stream>>>(h2, wo, bo, out);
}